// Round 9
// baseline (590.611 us; speedup 1.0000x reference)
//
#include <hip/hip_runtime.h>

// GADBase guided anisotropic diffusion on MI355X — round 9.
// R6/R7/R8 established: per-step cross-XCD neighbor sync costs ~5.3 us/step
// regardless of protocol (fence / flag / tagged-word). R9 eliminates sync:
// overlapped tiling. Each launch does 2 steps; blocks read a 9-px halo
// (margin math: diffuse -1 px, adjust rounds validity to the 8-aligned cell
// grid -> margin 9 = exactly 2 steps), compute step 1 on the 48x144
// cell-aligned extended region (cell means via LDS atomicAdd), apply ratios
// on read, compute step 2 on the interior with the R6 register/shuffle
// pattern, write interior only. 32 launches, no flags, no fences, no
// co-residency. Fully padded guard-16 planes (zeroed conductance guard =
// physical boundary condition) remove all boundary branches.

#define BB 2
#define HH 1024
#define WW 1024
#define NPIX (HH * WW)
#define CVN (1023 * 1024)
#define SHW (128 * 128)
#define LL 0.24f
#define KK2 (0.03f * 0.03f)
#define EPSF 1e-8f
#define DEPSF 0.1f

#define PW 1056           // padded plane width (guard 16 each side)
#define PG 16
#define PN (PW * PW)      // floats per padded plane
#define Q(y, x) (((y) + PG) * PW + ((x) + PG))

#define LW 152            // LDS row stride (floats, 16B-multiple)
#define TPB 256

__global__ void zero_kernel(float4* __restrict__ p) {
    size_t i = (size_t)blockIdx.x * TPB + threadIdx.x;
    p[i] = make_float4(0.f, 0.f, 0.f, 0.f);
}

__global__ void setup_kernel(const float* __restrict__ src, float* __restrict__ shiftOut) {
    int tid = threadIdx.x;
    float m = 1e30f;
    for (int i = tid; i < BB * SHW; i += TPB) m = fminf(m, src[i]);
    for (int off = 32; off > 0; off >>= 1) m = fminf(m, __shfl_down(m, off));
    __shared__ float sm[4];
    if ((tid & 63) == 0) sm[tid >> 6] = m;
    __syncthreads();
    if (tid == 0) {
        float mm = fminf(fminf(sm[0], sm[1]), fminf(sm[2], sm[3]));
        shiftOut[0] = (mm <= DEPSF) ? DEPSF : 0.0f;
    }
}

__global__ void init_kernel(const float* __restrict__ guide, const float* __restrict__ yb,
                            const float* __restrict__ shiftPtr, float* __restrict__ imA,
                            float* __restrict__ cv_out, float* __restrict__ ch_out,
                            float* __restrict__ cvq, float* __restrict__ chq) {
    int idx = blockIdx.x * blockDim.x + threadIdx.x;
    if (idx >= BB * NPIX) return;
    int b = idx >> 20;
    int p = idx & (NPIX - 1);
    int y = p >> 10;
    int x = p & 1023;
    const float* gb = guide + (size_t)b * 3 * NPIX;
    const float* yBb = yb + (size_t)b * NPIX;
    float c0 = yBb[p];
    imA[(size_t)b * PN + Q(y, x)] = c0 + shiftPtr[0];
    // shift cancels in finite diffs -> cv/ch from raw y_bicubic.
    if (y < HH - 1) {
        float d = fabsf(gb[p + WW] - gb[p])
                + fabsf(gb[NPIX + p + WW] - gb[NPIX + p])
                + fabsf(gb[2 * NPIX + p + WW] - gb[2 * NPIX + p])
                + fabsf(yBb[p + WW] - c0);
        d *= 0.25f;
        float v = 1.0f / (1.0f + (d * d) / KK2);
        cv_out[(size_t)b * CVN + y * WW + x] = v;
        cvq[(size_t)b * PN + Q(y, x)] = v;     // guard stays 0 (zero_kernel)
    }
    if (x < WW - 1) {
        float d = fabsf(gb[p + 1] - gb[p])
                + fabsf(gb[NPIX + p + 1] - gb[NPIX + p])
                + fabsf(gb[2 * NPIX + p + 1] - gb[2 * NPIX + p])
                + fabsf(yBb[p + 1] - c0);
        d *= 0.25f;
        float v = 1.0f / (1.0f + (d * d) / KK2);
        ch_out[(size_t)b * CVN + y * 1023 + x] = v;
        chq[(size_t)b * PN + Q(y, x)] = v;
    }
}

// One launch = 2 diffusion steps. 512 blocks, tile 32x128 per block.
__launch_bounds__(TPB, 2)
__global__ void step2_kernel(const float* __restrict__ imIn, float* __restrict__ imOut,
                             const float* __restrict__ cvq, const float* __restrict__ chq,
                             const float* __restrict__ src, const float* __restrict__ mask,
                             const float* __restrict__ shiftPtr, float* __restrict__ outC,
                             int last) {
    __shared__ float cur[50 * LW];
    __shared__ float nxt[50 * LW];
    __shared__ float cellSum[128];   // 6 x 18 cells
    __shared__ float ratioS[128];
    int blk = blockIdx.x;
    int b = blk >> 8;
    int r = blk & 255;
    int tileY = r >> 3;              // 0..31
    int tileX = r & 7;               // 0..7
    int tid = threadIdx.x;
    int ty0 = tileY * 32, tx0 = tileX * 128;
    float shift = shiftPtr[0];
    const float* imb = imIn + (size_t)b * PN;
    const float* cvb = cvq + (size_t)b * PN;
    const float* chb = chq + (size_t)b * PN;

    if (tid < 128) cellSum[tid] = 0.f;

    // ---- load extended region: rows -9..40 (50), cols -12..139 (38 float4) ----
#pragma unroll
    for (int j = 0; j < 8; ++j) {
        int i = j * TPB + tid;
        if (i < 1900) {
            int rr = i / 38, c4 = i - rr * 38;
            *(float4*)&cur[rr * LW + c4 * 4] =
                *(const float4*)&imb[Q(ty0 + rr - 9, tx0 + c4 * 4 - 12)];
        }
    }
    __syncthreads();

    // ---- step 1: compute on cell-aligned region rows -8..39, cols -8..135 ----
#pragma unroll
    for (int j = 0; j < 7; ++j) {
        int i = j * TPB + tid;
        if (i < 1728) {               // 48 rows x 36 float4
            int r2 = i / 36, c4 = i - r2 * 36;
            int lr = r2 + 1, lc = c4 * 4 + 4;
            float4 up = *(float4*)&cur[(lr - 1) * LW + lc];
            float4 cc = *(float4*)&cur[lr * LW + lc];
            float4 dn = *(float4*)&cur[(lr + 1) * LW + lc];
            float xl = cur[lr * LW + lc - 1];
            float xr = cur[lr * LW + lc + 4];
            int gy = ty0 + r2 - 8, gx = tx0 + c4 * 4 - 8;
            float4 cu = *(const float4*)&cvb[Q(gy - 1, gx)];
            float4 cd = *(const float4*)&cvb[Q(gy, gx)];
            float4 h4 = *(const float4*)&chb[Q(gy, gx)];
            float hm = chb[Q(gy, gx - 1)];
            float4 acc;
            acc.x = cc.x + LL * (cd.x * (dn.x - cc.x) - cu.x * (cc.x - up.x)
                               + h4.x * (cc.y - cc.x) - hm   * (cc.x - xl));
            acc.y = cc.y + LL * (cd.y * (dn.y - cc.y) - cu.y * (cc.y - up.y)
                               + h4.y * (cc.z - cc.y) - h4.x * (cc.y - cc.x));
            acc.z = cc.z + LL * (cd.z * (dn.z - cc.z) - cu.z * (cc.z - up.z)
                               + h4.z * (cc.w - cc.z) - h4.y * (cc.z - cc.y));
            acc.w = cc.w + LL * (cd.w * (dn.w - cc.w) - cu.w * (cc.w - up.w)
                               + h4.w * (xr   - cc.w) - h4.z * (cc.w - cc.z));
            *(float4*)&nxt[lr * LW + lc] = acc;
            atomicAdd(&cellSum[(r2 >> 3) * 18 + (c4 >> 1)],
                      acc.x + acc.y + acc.z + acc.w);
        }
    }
    __syncthreads();

    // ---- ratios for all 6x18 cells (clamped src/mask for out-of-image cells;
    //      their pixels sit behind zero conductance, any finite ratio is OK) ----
    if (tid < 108) {
        int cr = tid / 18, cc = tid - cr * 18;
        int gyc = (ty0 >> 3) + cr - 1;
        int gxc = (tx0 >> 3) + cc - 1;
        gyc = (gyc < 0) ? 0 : ((gyc > 127) ? 127 : gyc);
        gxc = (gxc < 0) ? 0 : ((gxc > 127) ? 127 : gxc);
        int sidx = b * SHW + gyc * 128 + gxc;
        ratioS[tid] = (mask[sidx] < 0.5f) ? 1.0f
                    : (src[sidx] + shift) / (cellSum[tid] * (1.0f / 64.0f) + EPSF);
    }
    __syncthreads();

    // ---- step 2: interior 32x128, R6 register/shuffle pattern; ratios of
    //      state t+1 applied lazily on every nxt read ----
    int cyL = tid >> 5;              // 0..7
    int g = tid & 31;
    int lx0 = g * 4, ly0 = cyL * 4;
    int ccI = (lx0 + 8) >> 3;
    int lcS = lx0 + 12;
    float4 nv[4];
    float4 rUp, rC;
    {
        int tr = ly0 - 1;
        rUp = *(float4*)&nxt[(tr + 9) * LW + lcS];
        float rt = ratioS[((tr + 8) >> 3) * 18 + ccI];
        rUp.x *= rt; rUp.y *= rt; rUp.z *= rt; rUp.w *= rt;
    }
    {
        rC = *(float4*)&nxt[(ly0 + 9) * LW + lcS];
        float rt = ratioS[((ly0 + 8) >> 3) * 18 + ccI];
        rC.x *= rt; rC.y *= rt; rC.z *= rt; rC.w *= rt;
    }
    float4 cu = *(const float4*)&cvb[Q(ty0 + ly0 - 1, tx0 + lx0)];
    float csum = 0.f;
#pragma unroll
    for (int k = 0; k < 4; ++k) {
        int tr = ly0 + 1 + k;
        float4 rDn = *(float4*)&nxt[(tr + 9) * LW + lcS];
        float rt = ratioS[((tr + 8) >> 3) * 18 + ccI];
        rDn.x *= rt; rDn.y *= rt; rDn.z *= rt; rDn.w *= rt;
        int gy = ty0 + ly0 + k, gx = tx0 + lx0;
        float4 cd = *(const float4*)&cvb[Q(gy, gx)];
        float4 h4 = *(const float4*)&chb[Q(gy, gx)];
        float hm = chb[Q(gy, gx - 1)];
        float xl = __shfl_up(rC.w, 1);
        float xr = __shfl_down(rC.x, 1);
        if (g == 0)
            xl = nxt[(ly0 + k + 9) * LW + 11] * ratioS[((ly0 + k + 8) >> 3) * 18 + 0];
        if (g == 31)
            xr = nxt[(ly0 + k + 9) * LW + 140] * ratioS[((ly0 + k + 8) >> 3) * 18 + 17];
        float4 acc;
        acc.x = rC.x + LL * (cd.x * (rDn.x - rC.x) - cu.x * (rC.x - rUp.x)
                           + h4.x * (rC.y - rC.x) - hm   * (rC.x - xl));
        acc.y = rC.y + LL * (cd.y * (rDn.y - rC.y) - cu.y * (rC.y - rUp.y)
                           + h4.y * (rC.z - rC.y) - h4.x * (rC.y - rC.x));
        acc.z = rC.z + LL * (cd.z * (rDn.z - rC.z) - cu.z * (rC.z - rUp.z)
                           + h4.z * (rC.w - rC.z) - h4.y * (rC.z - rC.y));
        acc.w = rC.w + LL * (cd.w * (rDn.w - rC.w) - cu.w * (rC.w - rUp.w)
                           + h4.w * (xr   - rC.w) - h4.z * (rC.w - rC.z));
        nv[k] = acc;
        csum += acc.x + acc.y + acc.z + acc.w;
        rUp = rC; rC = rDn; cu = cd;
    }
    csum += __shfl_xor(csum, 1);
    csum += __shfl_xor(csum, 32);    // 8x8 cell = lanes {tid,tid^1,tid^32,tid^33}
    int sidx2 = b * SHW + ((ty0 >> 3) + (cyL >> 1)) * 128 + (tx0 >> 3) + (g >> 1);
    float ratio2 = (mask[sidx2] < 0.5f) ? 1.0f
                 : (src[sidx2] + shift) / (csum * (1.0f / 64.0f) + EPSF);
    if (!last) {
        float* ob = imOut + (size_t)b * PN;
#pragma unroll
        for (int k = 0; k < 4; ++k) {
            float4 v = nv[k];
            v.x *= ratio2; v.y *= ratio2; v.z *= ratio2; v.w *= ratio2;
            *(float4*)&ob[Q(ty0 + ly0 + k, tx0 + lx0)] = v;
        }
    } else {
        float* ob = outC + (size_t)b * NPIX;
#pragma unroll
        for (int k = 0; k < 4; ++k) {
            float4 v = nv[k];
            v.x = v.x * ratio2 - shift; v.y = v.y * ratio2 - shift;
            v.z = v.z * ratio2 - shift; v.w = v.w * ratio2 - shift;
            *(float4*)&ob[(size_t)(ty0 + ly0 + k) * WW + tx0 + lx0] = v;
        }
    }
}

extern "C" void kernel_launch(void* const* d_in, const int* in_sizes, int n_in,
                              void* d_out, int out_size, void* d_ws, size_t ws_size,
                              hipStream_t stream) {
    const float* guide = (const float*)d_in[0];   // [2,3,1024,1024]
    const float* yb    = (const float*)d_in[1];   // [2,1,1024,1024]
    const float* src   = (const float*)d_in[2];   // [2,1,128,128]
    const float* mask  = (const float*)d_in[3];   // [2,1,128,128]

    float* out    = (float*)d_out;                       // y_pred [2,1,1024,1024]
    float* out_cv = out + (size_t)BB * NPIX;
    float* out_ch = out_cv + (size_t)BB * CVN;

    float* wsf  = (float*)d_ws;
    float* shift = wsf;                                  // [256] slot
    float* imA  = wsf + 256;                             // 2 padded planes
    float* imB  = imA + (size_t)BB * PN;
    float* cvq  = imB + (size_t)BB * PN;                 // 2 padded planes
    float* chq  = cvq + (size_t)BB * PN;                 // 2 padded planes

    // zero conductance planes (guards must be exactly 0 = boundary condition)
    zero_kernel<<<PN / TPB, TPB, 0, stream>>>((float4*)cvq);   // 4*PN floats = PN float4
    setup_kernel<<<1, TPB, 0, stream>>>(src, shift);
    init_kernel<<<(BB * NPIX) / TPB, TPB, 0, stream>>>(guide, yb, shift, imA,
                                                       out_cv, out_ch, cvq, chq);

    // 32 launches x 2 steps, ping-pong imA <-> imB; last writes compact out.
    for (int p = 0; p < 32; ++p) {
        const float* in = (p & 1) ? imB : imA;
        float* o = (p & 1) ? imA : imB;
        step2_kernel<<<BB * 256, TPB, 0, stream>>>(in, o, cvq, chq, src, mask,
                                                   shift, out, (p == 31) ? 1 : 0);
    }
}